// Round 11
// baseline (687.458 us; speedup 1.0000x reference)
//
#include <hip/hip_runtime.h>
#include <hip/hip_bf16.h>
#include <math.h>

#define N_NODES 10000
#define M_PAD   10112          // 79 * 128
#define N_EDGES 160000
#define FEAT 739
#define KD_PAD 768             // FEAT padded to 32
#define CCH 256
#define HEADS 8
#define LAYERS 4
#define NGR 16
#define HC 2048                // HEADS * CCH
#define HC2 4096               // xl|xr concatenated row
#define E_TOT (N_EDGES + N_NODES)

typedef _Float16 half8_t __attribute__((ext_vector_type(8)));
typedef _Float16 half4_t __attribute__((ext_vector_type(4)));
typedef _Float16 half2_t __attribute__((ext_vector_type(2)));
typedef float    f32x4   __attribute__((ext_vector_type(4)));

__device__ __forceinline__ void gload16(const void* g, void* l) {
  __builtin_amdgcn_global_load_lds(
      (const __attribute__((address_space(1))) void*)g,
      (__attribute__((address_space(3))) void*)l, 16, 0, 0);
}

// ---------------------------------------------------------------- MFMA GEMM (fp16 in, fp32 acc)
// 128x128 tile, BK=32 dbuf, gload16 staging, LDS-bounce coalesced epilogue.
__global__ __launch_bounds__(256) void gemm_h16(
    const _Float16* __restrict__ A,   // [M_PAD][K]
    const _Float16* __restrict__ BT,  // [N][K]
    _Float16* __restrict__ C16,       // [M][N]
    const float* __restrict__ bias,   // [N] or null
    int M, int N, int K)
{
  __shared__ __align__(16) char smem[32768];
  _Float16 (*As)[128][32] = (_Float16(*)[128][32])smem;            // [2][128][32]
  _Float16 (*Bs)[128][32] = (_Float16(*)[128][32])(smem + 16384);  // [2][128][32]
  const int tid  = threadIdx.x;
  const int wave = tid >> 6, lane = tid & 63;
  const int wm = wave >> 1, wn = wave & 1;
  const int m0 = blockIdx.y * 128, n0 = blockIdx.x * 128;
  const int l15 = lane & 15, l4 = lane >> 4;

  f32x4 acc[4][4];
  #pragma unroll
  for (int i = 0; i < 4; i++)
    #pragma unroll
    for (int j = 0; j < 4; j++) acc[i][j] = (f32x4){0.f, 0.f, 0.f, 0.f};

  auto stage = [&](int buf, int k0) {
    #pragma unroll
    for (int i = 0; i < 2; i++) {
      int q = i * 256 + tid;
      int row = q >> 2, ch = (q & 3) * 8;
      gload16(&A[(size_t)(m0 + row) * K + k0 + ch], &As[buf][row][ch]);
    }
    #pragma unroll
    for (int i = 0; i < 2; i++) {
      int q = i * 256 + tid;
      int row = q >> 2, ch = (q & 3) * 8;
      gload16(&BT[(size_t)(n0 + row) * K + k0 + ch], &Bs[buf][row][ch]);
    }
  };

  const int NT = K >> 5;
  stage(0, 0);
  for (int t = 0; t < NT; t++) {
    __syncthreads();                     // buf t&1 staged + safe to reuse
    if (t + 1 < NT) stage((t + 1) & 1, (t + 1) << 5);
    const int b = t & 1;
    half8_t af[4], bf[4];
    #pragma unroll
    for (int f = 0; f < 4; f++)
      af[f] = *(const half8_t*)&As[b][wm * 64 + f * 16 + l15][l4 * 8];
    #pragma unroll
    for (int f = 0; f < 4; f++)
      bf[f] = *(const half8_t*)&Bs[b][wn * 64 + f * 16 + l15][l4 * 8];
    #pragma unroll
    for (int i = 0; i < 4; i++)
      #pragma unroll
      for (int j = 0; j < 4; j++)
        acc[i][j] = __builtin_amdgcn_mfma_f32_16x16x32_f16(af[i], bf[j], acc[i][j], 0, 0, 0);
  }

  // ---- epilogue: acc -> LDS fp16 tile -> coalesced half8 stores
  __syncthreads();                       // done with As/Bs
  _Float16* ct = (_Float16*)smem;        // [128][128]
  #pragma unroll
  for (int j = 0; j < 4; j++) {
    const int cl = wn * 64 + j * 16 + l15;
    const float bv = bias ? bias[n0 + cl] : 0.f;
    #pragma unroll
    for (int i = 0; i < 4; i++) {
      #pragma unroll
      for (int r = 0; r < 4; r++) {
        const int rl = wm * 64 + i * 16 + l4 * 4 + r;
        ct[rl * 128 + cl] = (_Float16)(acc[i][j][r] + bv);
      }
    }
  }
  __syncthreads();
  #pragma unroll
  for (int q = 0; q < 8; q++) {
    const int idx = q * 256 + tid;       // 0..2047
    const int row = idx >> 4, c8 = (idx & 15) * 8;
    const int grow = m0 + row;
    if (grow < M)
      *(half8_t*)&C16[(size_t)grow * N + n0 + c8] = *(const half8_t*)&ct[row * 128 + c8];
  }
}

// ---------------------------------------------------------------- converts / transposes
// dense weight transpose (K=FEAT rows -> Kpad)
__global__ __launch_bounds__(256) void transpose_w(
    const float* __restrict__ in, _Float16* __restrict__ out, int K, int N, int Kpad)
{
  __shared__ float tile[32][33];
  const int kb = blockIdx.y * 32, nb = blockIdx.x * 32;
  const int tx = threadIdx.x & 31, ty = threadIdx.x >> 5;
  #pragma unroll
  for (int i = 0; i < 32; i += 8) {
    int k = kb + ty + i;
    tile[ty + i][tx] = (k < K) ? in[(size_t)k * N + nb + tx] : 0.f;
  }
  __syncthreads();
  #pragma unroll
  for (int i = 0; i < 32; i += 8) {
    int n = nb + ty + i;
    out[(size_t)n * Kpad + kb + tx] = (_Float16)tile[tx][ty + i];
  }
}

// all 8 layer-weight transposes in ONE launch: z = l*2 + which(0=wl,1=wr)
__global__ __launch_bounds__(256) void transpose_w8(
    const float* __restrict__ wl, const float* __restrict__ wr,
    _Float16* __restrict__ wcat)
{
  __shared__ float tile[32][33];
  const int z = blockIdx.z;
  const int l = z >> 1, which = z & 1;
  const float* in = (which ? wr : wl) + (size_t)l * CCH * HC;
  _Float16* out = wcat + (size_t)l * HC2 * CCH + (size_t)which * HC * CCH;
  const int kb = blockIdx.y * 32, nb = blockIdx.x * 32;
  const int tx = threadIdx.x & 31, ty = threadIdx.x >> 5;
  #pragma unroll
  for (int i = 0; i < 32; i += 8)
    tile[ty + i][tx] = in[(size_t)(kb + ty + i) * HC + nb + tx];
  __syncthreads();
  #pragma unroll
  for (int i = 0; i < 32; i += 8)
    out[(size_t)(nb + ty + i) * CCH + kb + tx] = (_Float16)tile[tx][ty + i];
}

__global__ void conv_x(const float* __restrict__ x, _Float16* __restrict__ x16)
{
  const int r = blockIdx.y;
  const int c = blockIdx.x * 256 + threadIdx.x;
  float v = (r < N_NODES && c < FEAT) ? x[(size_t)r * FEAT + c] : 0.f;
  x16[(size_t)r * KD_PAD + c] = (_Float16)v;
}

// ---------------------------------------------------------------- CSR build
__global__ void degree_kernel(const int* __restrict__ ei, int* __restrict__ cnt)
{
  int e = blockIdx.x * 256 + threadIdx.x;
  if (e >= E_TOT) return;
  int d = (e < N_EDGES) ? ei[N_EDGES + e] : (e - N_EDGES);
  atomicAdd(&cnt[d], 1);
}

__global__ void scan_kernel(const int* __restrict__ cnt, int* __restrict__ off, int n)
{
  __shared__ int part[1024];
  const int t = threadIdx.x;
  const int chunk = (n + 1023) / 1024;
  int s = 0;
  for (int i = 0; i < chunk; i++) {
    int idx = t * chunk + i;
    if (idx < n) s += cnt[idx];
  }
  part[t] = s;
  __syncthreads();
  for (int d = 1; d < 1024; d <<= 1) {
    int v = (t >= d) ? part[t - d] : 0;
    __syncthreads();
    part[t] += v;
    __syncthreads();
  }
  int run = (t == 0) ? 0 : part[t - 1];
  for (int i = 0; i < chunk; i++) {
    int idx = t * chunk + i;
    if (idx < n) { off[idx] = run; run += cnt[idx]; }
  }
  if (t == 1023) off[n] = part[1023];
}

__global__ void copy_kernel(const int* __restrict__ src, int* __restrict__ dst, int n)
{
  int i = blockIdx.x * 256 + threadIdx.x;
  if (i < n) dst[i] = src[i];
}

// csr entries pre-scaled: src * HC2 (fits int: 10000*4096 = 41M)
__global__ void fill_kernel(const int* __restrict__ ei, int* __restrict__ cursor,
                            int* __restrict__ csr)
{
  int e = blockIdx.x * 256 + threadIdx.x;
  if (e >= E_TOT) return;
  int s, d;
  if (e < N_EDGES) { s = ei[e]; d = ei[N_EDGES + e]; }
  else             { s = e - N_EDGES; d = s; }
  int pos = atomicAdd(&cursor[d], 1);
  csr[pos] = s * HC2;
}

// sort each node's neighbor list ascending -> GPU-wide phase-coherent gather
// order (all co-resident blocks sweep src space together -> better L2 hit).
__global__ __launch_bounds__(256) void sort_csr(const int* __restrict__ off,
                                                int* __restrict__ csr)
{
  __shared__ int buf[5120];
  const int n0 = blockIdx.x * 256;
  const int t = threadIdx.x;
  const int n = n0 + t;
  const int hi = min(n0 + 256, N_NODES);
  const int gs = off[n0], ge = off[hi];
  const int total = ge - gs;
  if (total <= 5120) {
    for (int i = t; i < total; i += 256) buf[i] = csr[gs + i];
    __syncthreads();
    if (n < N_NODES) {
      const int a = off[n] - gs, b = off[n + 1] - gs;
      for (int i = a + 1; i < b; i++) {
        int v = buf[i], j = i - 1;
        while (j >= a && buf[j] > v) { buf[j + 1] = buf[j]; j--; }
        buf[j + 1] = v;
      }
    }
    __syncthreads();
    for (int i = t; i < total; i += 256) csr[gs + i] = buf[i];
  } else if (n < N_NODES) {            // statistical overflow fallback
    const int a = off[n], b = off[n + 1];
    for (int i = a + 1; i < b; i++) {
      int v = csr[i], j = i - 1;
      while (j >= a && csr[j] > v) { csr[j + 1] = csr[j]; j--; }
      csr[j + 1] = v;
    }
  }
}

__global__ void gbound_kernel(const int* __restrict__ batch, int* __restrict__ goff)
{
  int n = blockIdx.x * 256 + threadIdx.x;
  if (n >= N_NODES) return;
  if (n == 0) {
    for (int g = 0; g <= batch[0]; g++) goff[g] = 0;
  } else {
    int b0 = batch[n - 1], b1 = batch[n];
    for (int g = b0 + 1; g <= b1; g++) goff[g] = n;
  }
  if (n == N_NODES - 1) {
    for (int g = batch[n] + 1; g <= NGR; g++) goff[g] = N_NODES;
  }
}

// ---------------------------------------------------------------- fused GATv2 edge pass
// 1 block = 1 dst node; 8 heads x 32 lanes, 8 ch/lane. 8-edge ILP, single
// rescale check/group, clamped prefetch, fdot2 scores, fp16 packed aggregation.
__global__ __launch_bounds__(256) void gat_edge(
    const _Float16* __restrict__ xlr,
    const int* __restrict__ off, const int* __restrict__ csr,
    const float* __restrict__ att, const float* __restrict__ bias,
    float* __restrict__ hout, _Float16* __restrict__ hout16)
{
  __shared__ float red2[8][256];
  const int n = blockIdx.x;
  const int t = threadIdx.x;
  const size_t fo = (size_t)(t >> 5) * CCH + (t & 31) * 8;

  half8_t vxr = *(const half8_t*)&xlr[(size_t)n * HC2 + HC + fo];
  half8_t vat;
  {
    float4 a0 = *(const float4*)&att[fo];
    float4 a1 = *(const float4*)&att[fo + 4];
    vat[0] = (_Float16)a0.x; vat[1] = (_Float16)a0.y;
    vat[2] = (_Float16)a0.z; vat[3] = (_Float16)a0.w;
    vat[4] = (_Float16)a1.x; vat[5] = (_Float16)a1.y;
    vat[6] = (_Float16)a1.z; vat[7] = (_Float16)a1.w;
  }

  float m_run = -INFINITY, d_run = 0.f;
  half8_t accv = (half8_t)(_Float16)0.f;   // fp16 packed accumulator

  const int e0 = off[n], e1 = off[n + 1];
  const int last = e1 - 1;
  const _Float16* base = xlr + fo;

  auto loadrow = [&](int idx) -> half8_t {
    return *(const half8_t*)(base + (unsigned)csr[min(idx, last)]);
  };

  half8_t cv[8], nv[8];
  #pragma unroll
  for (int k = 0; k < 8; k++) cv[k] = loadrow(e0 + k);
  const int niter = (e1 - e0 + 7) >> 3;
  int i = e0;

  for (int q = 0; q < niter; q++) {
    #pragma unroll
    for (int k = 0; k < 8; k++) nv[k] = loadrow(i + 8 + k);

    float p[8];
    #pragma unroll
    for (int k = 0; k < 8; k++) {
      half8_t m  = cv[k] + vxr;
      half8_t lm = __builtin_elementwise_max(m, m * (_Float16)0.2f);
      float s = 0.f;
      #pragma unroll
      for (int d2 = 0; d2 < 4; d2++) {
        half2_t a  = { vat[2 * d2], vat[2 * d2 + 1] };
        half2_t x0 = { lm[2 * d2],  lm[2 * d2 + 1]  };
        s = __builtin_amdgcn_fdot2(x0, a, s, false);
      }
      p[k] = s;
    }
    #pragma unroll
    for (int d2 = 1; d2 < 32; d2 <<= 1)
      #pragma unroll
      for (int k = 0; k < 8; k++)
        p[k] += __shfl_xor(p[k], d2);
    #pragma unroll
    for (int k = 1; k < 8; k++)
      if (i + k >= e1) p[k] = -INFINITY;    // masked tail edges -> pe=0

    float m01 = fmaxf(p[0], p[1]), m23 = fmaxf(p[2], p[3]);
    float m45 = fmaxf(p[4], p[5]), m67 = fmaxf(p[6], p[7]);
    float mg = fmaxf(fmaxf(m01, m23), fmaxf(m45, m67));
    if (mg > m_run) {
      float sc = __expf(m_run - mg);        // exp(-inf)=0 on first group
      d_run *= sc;
      accv = accv * (_Float16)sc;
      m_run = mg;
    }
    float pe[8];
    #pragma unroll
    for (int k = 0; k < 8; k++) pe[k] = __expf(p[k] - m_run);
    d_run += ((pe[0] + pe[1]) + (pe[2] + pe[3])) + ((pe[4] + pe[5]) + (pe[6] + pe[7]));
    #pragma unroll
    for (int k = 0; k < 8; k++)
      accv = accv + cv[k] * (_Float16)pe[k];  // v_pk_fma_f16 x4 each
    #pragma unroll
    for (int k = 0; k < 8; k++) cv[k] = nv[k];
    i += 8;
  }

  const float w = 0.125f / (d_run + 1e-16f);
  #pragma unroll
  for (int j = 0; j < 8; j++) red2[j][t] = (float)accv[j] * w;
  __syncthreads();
  if (t < 32) {
    #pragma unroll
    for (int j = 0; j < 8; j++) {
      float s2 = 0.f;
      #pragma unroll
      for (int hh = 0; hh < 8; hh++) s2 += red2[j][hh * 32 + t];
      s2 += bias[t * 8 + j];
      if (hout) hout[(size_t)n * CCH + t * 8 + j] = s2;
      hout16[(size_t)n * CCH + t * 8 + j] = (_Float16)s2;
    }
  }
}

// ---------------------------------------------------------------- pool + head
__global__ __launch_bounds__(256) void pool_kernel2(
    const float* __restrict__ h, const int* __restrict__ goff,
    float* __restrict__ pooled)
{
  const int g = blockIdx.x, s = blockIdx.y, t = threadIdx.x;
  const int n0 = goff[g], n1 = goff[g + 1];
  const int len = n1 - n0;
  const int chunk = (len + 7) / 8;
  const int a = n0 + s * chunk;
  const int b = min(a + chunk, n1);
  float sum = 0.f;
  for (int n = a; n < b; n++) sum += h[(size_t)n * CCH + t];
  if (len > 0) atomicAdd(&pooled[g * CCH + t], sum);
}

__global__ void head_kernel(const float* __restrict__ pooled, const int* __restrict__ goff,
                            const float* __restrict__ hw, const float* __restrict__ hb,
                            float* __restrict__ out)
{
  __shared__ float r[256];
  const int g = blockIdx.x, t = threadIdx.x;
  float c = (float)(goff[g + 1] - goff[g]);
  if (c < 1.f) c = 1.f;
  r[t] = pooled[g * CCH + t] / c * hw[t];
  __syncthreads();
  for (int s2 = 128; s2 > 0; s2 >>= 1) {
    if (t < s2) r[t] += r[t + s2];
    __syncthreads();
  }
  if (t == 0) out[g] = r[0] + hb[0];
}

// ---------------------------------------------------------------- launcher
extern "C" void kernel_launch(void* const* d_in, const int* in_sizes, int n_in,
                              void* d_out, int out_size, void* d_ws, size_t ws_size,
                              hipStream_t stream)
{
  const float* x        = (const float*)d_in[0];
  const int*   ei       = (const int*)d_in[1];
  const int*   batch    = (const int*)d_in[2];
  const float* dense_w  = (const float*)d_in[3];
  const float* dense_b  = (const float*)d_in[4];
  const float* conv_wl  = (const float*)d_in[5];
  const float* conv_wr  = (const float*)d_in[6];
  const float* conv_att = (const float*)d_in[7];
  const float* conv_b   = (const float*)d_in[8];
  const float* head_w   = (const float*)d_in[9];
  const float* head_b   = (const float*)d_in[10];
  float* out = (float*)d_out;

  char* ws = (char*)d_ws;
  size_t off_b = 0;
  auto alloc = [&](size_t bytes) -> char* {
    char* r = ws + off_b;
    off_b += (bytes + 255) & ~(size_t)255;
    return r;
  };
  float*     h      = (float*)alloc((size_t)N_NODES * CCH * 4);
  _Float16*  h16    = (_Float16*)alloc((size_t)M_PAD * CCH * 2);
  _Float16*  x16    = (_Float16*)alloc((size_t)M_PAD * KD_PAD * 2);
  _Float16*  xlr16  = (_Float16*)alloc((size_t)M_PAD * HC2 * 2);
  _Float16*  wdT    = (_Float16*)alloc((size_t)CCH * KD_PAD * 2);
  _Float16*  wcat   = (_Float16*)alloc((size_t)LAYERS * HC2 * CCH * 2);
  int*   offs   = (int*)alloc((N_NODES + 1) * 4);
  int*   cnt    = (int*)alloc(N_NODES * 4);
  int*   csr    = (int*)alloc(E_TOT * 4);
  int*   goff   = (int*)alloc((NGR + 1) * 4);
  float* pooled = (float*)alloc(NGR * CCH * 4);

  // ---- CSR by dst (+ per-node neighbor sort) + graph boundaries
  hipMemsetAsync(cnt, 0, N_NODES * 4, stream);
  degree_kernel<<<(E_TOT + 255) / 256, 256, 0, stream>>>(ei, cnt);
  scan_kernel<<<1, 1024, 0, stream>>>(cnt, offs, N_NODES);
  copy_kernel<<<(N_NODES + 255) / 256, 256, 0, stream>>>(offs, cnt, N_NODES);
  fill_kernel<<<(E_TOT + 255) / 256, 256, 0, stream>>>(ei, cnt, csr);
  sort_csr<<<(N_NODES + 255) / 256, 256, 0, stream>>>(offs, csr);
  gbound_kernel<<<(N_NODES + 255) / 256, 256, 0, stream>>>(batch, goff);

  // ---- fp16 conversions / weight transposes (wl|wr concatenated)
  {
    dim3 g(KD_PAD / 256, M_PAD);
    conv_x<<<g, 256, 0, stream>>>(x, x16);
  }
  transpose_w<<<dim3(CCH / 32, KD_PAD / 32), 256, 0, stream>>>(dense_w, wdT, FEAT, CCH, KD_PAD);
  transpose_w8<<<dim3(HC / 32, CCH / 32, 2 * LAYERS), 256, 0, stream>>>(
      conv_wl, conv_wr, wcat);

  // ---- dense: h16 = fp16(x @ dense_w + dense_b)
  gemm_h16<<<dim3(CCH / 128, M_PAD / 128), 256, 0, stream>>>(
      x16, wdT, h16, dense_b, N_NODES, CCH, KD_PAD);

  // ---- 4 GATv2 layers (fp32 h only from the last one)
  for (int l = 0; l < LAYERS; l++) {
    gemm_h16<<<dim3(HC2 / 128, M_PAD / 128), 256, 0, stream>>>(
        h16, wcat + (size_t)l * HC2 * CCH, xlr16, nullptr, N_NODES, HC2, CCH);
    gat_edge<<<N_NODES, 256, 0, stream>>>(xlr16, offs, csr,
                                          conv_att + (size_t)l * HC,
                                          conv_b + (size_t)l * CCH,
                                          (l == LAYERS - 1) ? h : nullptr, h16);
  }

  // ---- global mean pool + head
  hipMemsetAsync(pooled, 0, NGR * CCH * 4, stream);
  pool_kernel2<<<dim3(NGR, 8), 256, 0, stream>>>(h, goff, pooled);
  head_kernel<<<NGR, 256, 0, stream>>>(pooled, goff, head_w, head_b, out);
}

// Round 12
// 634.275 us; speedup vs baseline: 1.0838x; 1.0838x over previous
//
#include <hip/hip_runtime.h>
#include <hip/hip_bf16.h>
#include <math.h>

#define N_NODES 10000
#define M_PAD   10112          // 79 * 128
#define N_EDGES 160000
#define FEAT 739
#define KD_PAD 768             // FEAT padded to 32
#define CCH 256
#define HEADS 8
#define LAYERS 4
#define NGR 16
#define HC 2048                // HEADS * CCH
#define HC2 4096               // xl|xr concatenated row
#define E_TOT (N_EDGES + N_NODES)

typedef _Float16 half8_t __attribute__((ext_vector_type(8)));
typedef _Float16 half2_t __attribute__((ext_vector_type(2)));
typedef float    f32x4   __attribute__((ext_vector_type(4)));

__device__ __forceinline__ void gload16(const void* g, void* l) {
  __builtin_amdgcn_global_load_lds(
      (const __attribute__((address_space(1))) void*)g,
      (__attribute__((address_space(3))) void*)l, 16, 0, 0);
}

// ---------------------------------------------------------------- MFMA GEMM (fp16 in, fp32 acc)
// 128x128 tile, BK=32 dbuf, gload16 staging, LDS-bounce coalesced epilogue.
__global__ __launch_bounds__(256) void gemm_h16(
    const _Float16* __restrict__ A,   // [M_PAD][K]
    const _Float16* __restrict__ BT,  // [N][K]
    _Float16* __restrict__ C16,       // [M][N]
    const float* __restrict__ bias,   // [N] or null
    int M, int N, int K)
{
  __shared__ __align__(16) char smem[32768];
  _Float16 (*As)[128][32] = (_Float16(*)[128][32])smem;            // [2][128][32]
  _Float16 (*Bs)[128][32] = (_Float16(*)[128][32])(smem + 16384);  // [2][128][32]
  const int tid  = threadIdx.x;
  const int wave = tid >> 6, lane = tid & 63;
  const int wm = wave >> 1, wn = wave & 1;
  const int m0 = blockIdx.y * 128, n0 = blockIdx.x * 128;
  const int l15 = lane & 15, l4 = lane >> 4;

  f32x4 acc[4][4];
  #pragma unroll
  for (int i = 0; i < 4; i++)
    #pragma unroll
    for (int j = 0; j < 4; j++) acc[i][j] = (f32x4){0.f, 0.f, 0.f, 0.f};

  auto stage = [&](int buf, int k0) {
    #pragma unroll
    for (int i = 0; i < 2; i++) {
      int q = i * 256 + tid;
      int row = q >> 2, ch = (q & 3) * 8;
      gload16(&A[(size_t)(m0 + row) * K + k0 + ch], &As[buf][row][ch]);
    }
    #pragma unroll
    for (int i = 0; i < 2; i++) {
      int q = i * 256 + tid;
      int row = q >> 2, ch = (q & 3) * 8;
      gload16(&BT[(size_t)(n0 + row) * K + k0 + ch], &Bs[buf][row][ch]);
    }
  };

  const int NT = K >> 5;
  stage(0, 0);
  for (int t = 0; t < NT; t++) {
    __syncthreads();                     // buf t&1 staged + safe to reuse
    if (t + 1 < NT) stage((t + 1) & 1, (t + 1) << 5);
    const int b = t & 1;
    half8_t af[4], bf[4];
    #pragma unroll
    for (int f = 0; f < 4; f++)
      af[f] = *(const half8_t*)&As[b][wm * 64 + f * 16 + l15][l4 * 8];
    #pragma unroll
    for (int f = 0; f < 4; f++)
      bf[f] = *(const half8_t*)&Bs[b][wn * 64 + f * 16 + l15][l4 * 8];
    #pragma unroll
    for (int i = 0; i < 4; i++)
      #pragma unroll
      for (int j = 0; j < 4; j++)
        acc[i][j] = __builtin_amdgcn_mfma_f32_16x16x32_f16(af[i], bf[j], acc[i][j], 0, 0, 0);
  }

  // ---- epilogue: acc -> LDS fp16 tile -> coalesced half8 stores
  __syncthreads();                       // done with As/Bs
  _Float16* ct = (_Float16*)smem;        // [128][128]
  #pragma unroll
  for (int j = 0; j < 4; j++) {
    const int cl = wn * 64 + j * 16 + l15;
    const float bv = bias ? bias[n0 + cl] : 0.f;
    #pragma unroll
    for (int i = 0; i < 4; i++) {
      #pragma unroll
      for (int r = 0; r < 4; r++) {
        const int rl = wm * 64 + i * 16 + l4 * 4 + r;
        ct[rl * 128 + cl] = (_Float16)(acc[i][j][r] + bv);
      }
    }
  }
  __syncthreads();
  #pragma unroll
  for (int q = 0; q < 8; q++) {
    const int idx = q * 256 + tid;       // 0..2047
    const int row = idx >> 4, c8 = (idx & 15) * 8;
    const int grow = m0 + row;
    if (grow < M)
      *(half8_t*)&C16[(size_t)grow * N + n0 + c8] = *(const half8_t*)&ct[row * 128 + c8];
  }
}

// ---------------------------------------------------------------- converts / transposes
__global__ __launch_bounds__(256) void transpose_w(
    const float* __restrict__ in, _Float16* __restrict__ out, int K, int N, int Kpad)
{
  __shared__ float tile[32][33];
  const int kb = blockIdx.y * 32, nb = blockIdx.x * 32;
  const int tx = threadIdx.x & 31, ty = threadIdx.x >> 5;
  #pragma unroll
  for (int i = 0; i < 32; i += 8) {
    int k = kb + ty + i;
    tile[ty + i][tx] = (k < K) ? in[(size_t)k * N + nb + tx] : 0.f;
  }
  __syncthreads();
  #pragma unroll
  for (int i = 0; i < 32; i += 8) {
    int n = nb + ty + i;
    out[(size_t)n * Kpad + kb + tx] = (_Float16)tile[tx][ty + i];
  }
}

// all 8 layer-weight transposes in ONE launch: z = l*2 + which(0=wl,1=wr)
__global__ __launch_bounds__(256) void transpose_w8(
    const float* __restrict__ wl, const float* __restrict__ wr,
    _Float16* __restrict__ wcat)
{
  __shared__ float tile[32][33];
  const int z = blockIdx.z;
  const int l = z >> 1, which = z & 1;
  const float* in = (which ? wr : wl) + (size_t)l * CCH * HC;
  _Float16* out = wcat + (size_t)l * HC2 * CCH + (size_t)which * HC * CCH;
  const int kb = blockIdx.y * 32, nb = blockIdx.x * 32;
  const int tx = threadIdx.x & 31, ty = threadIdx.x >> 5;
  #pragma unroll
  for (int i = 0; i < 32; i += 8)
    tile[ty + i][tx] = in[(size_t)(kb + ty + i) * HC + nb + tx];
  __syncthreads();
  #pragma unroll
  for (int i = 0; i < 32; i += 8)
    out[(size_t)(nb + ty + i) * CCH + kb + tx] = (_Float16)tile[tx][ty + i];
}

__global__ void conv_x(const float* __restrict__ x, _Float16* __restrict__ x16)
{
  const int r = blockIdx.y;
  const int c = blockIdx.x * 256 + threadIdx.x;
  float v = (r < N_NODES && c < FEAT) ? x[(size_t)r * FEAT + c] : 0.f;
  x16[(size_t)r * KD_PAD + c] = (_Float16)v;
}

// ---------------------------------------------------------------- CSR build
__global__ void degree_kernel(const int* __restrict__ ei, int* __restrict__ cnt)
{
  int e = blockIdx.x * 256 + threadIdx.x;
  if (e >= E_TOT) return;
  int d = (e < N_EDGES) ? ei[N_EDGES + e] : (e - N_EDGES);
  atomicAdd(&cnt[d], 1);
}

__global__ void scan_kernel(const int* __restrict__ cnt, int* __restrict__ off, int n)
{
  __shared__ int part[1024];
  const int t = threadIdx.x;
  const int chunk = (n + 1023) / 1024;
  int s = 0;
  for (int i = 0; i < chunk; i++) {
    int idx = t * chunk + i;
    if (idx < n) s += cnt[idx];
  }
  part[t] = s;
  __syncthreads();
  for (int d = 1; d < 1024; d <<= 1) {
    int v = (t >= d) ? part[t - d] : 0;
    __syncthreads();
    part[t] += v;
    __syncthreads();
  }
  int run = (t == 0) ? 0 : part[t - 1];
  for (int i = 0; i < chunk; i++) {
    int idx = t * chunk + i;
    if (idx < n) { off[idx] = run; run += cnt[idx]; }
  }
  if (t == 1023) off[n] = part[1023];
}

__global__ void copy_kernel(const int* __restrict__ src, int* __restrict__ dst, int n)
{
  int i = blockIdx.x * 256 + threadIdx.x;
  if (i < n) dst[i] = src[i];
}

// csr entries pre-scaled: src * HC2 (fits int: 10000*4096 = 41M)
__global__ void fill_kernel(const int* __restrict__ ei, int* __restrict__ cursor,
                            int* __restrict__ csr)
{
  int e = blockIdx.x * 256 + threadIdx.x;
  if (e >= E_TOT) return;
  int s, d;
  if (e < N_EDGES) { s = ei[e]; d = ei[N_EDGES + e]; }
  else             { s = e - N_EDGES; d = s; }
  int pos = atomicAdd(&cursor[d], 1);
  csr[pos] = s * HC2;
}

__global__ void gbound_kernel(const int* __restrict__ batch, int* __restrict__ goff)
{
  int n = blockIdx.x * 256 + threadIdx.x;
  if (n >= N_NODES) return;
  if (n == 0) {
    for (int g = 0; g <= batch[0]; g++) goff[g] = 0;
  } else {
    int b0 = batch[n - 1], b1 = batch[n];
    for (int g = b0 + 1; g <= b1; g++) goff[g] = n;
  }
  if (n == N_NODES - 1) {
    for (int g = batch[n] + 1; g <= NGR; g++) goff[g] = N_NODES;
  }
}

// ---------------------------------------------------------------- fused GATv2 edge pass
// 1 block = 1 dst node; 8 heads x 32 lanes, 8 ch/lane. 8-edge ILP, single
// rescale check/group, clamped prefetch, fdot2 scores, fp16 packed aggregation.
__global__ __launch_bounds__(256) void gat_edge(
    const _Float16* __restrict__ xlr,
    const int* __restrict__ off, const int* __restrict__ csr,
    const float* __restrict__ att, const float* __restrict__ bias,
    _Float16* __restrict__ hout16)
{
  __shared__ float red2[8][256];
  const int n = blockIdx.x;
  const int t = threadIdx.x;
  const size_t fo = (size_t)(t >> 5) * CCH + (t & 31) * 8;

  half8_t vxr = *(const half8_t*)&xlr[(size_t)n * HC2 + HC + fo];
  half8_t vat;
  {
    float4 a0 = *(const float4*)&att[fo];
    float4 a1 = *(const float4*)&att[fo + 4];
    vat[0] = (_Float16)a0.x; vat[1] = (_Float16)a0.y;
    vat[2] = (_Float16)a0.z; vat[3] = (_Float16)a0.w;
    vat[4] = (_Float16)a1.x; vat[5] = (_Float16)a1.y;
    vat[6] = (_Float16)a1.z; vat[7] = (_Float16)a1.w;
  }

  float m_run = -INFINITY, d_run = 0.f;
  half8_t accv = (half8_t)(_Float16)0.f;   // fp16 packed accumulator

  const int e0 = off[n], e1 = off[n + 1];
  const int last = e1 - 1;
  const _Float16* base = xlr + fo;

  auto loadrow = [&](int idx) -> half8_t {
    return *(const half8_t*)(base + (unsigned)csr[min(idx, last)]);
  };

  half8_t cv[8], nv[8];
  #pragma unroll
  for (int k = 0; k < 8; k++) cv[k] = loadrow(e0 + k);
  const int niter = (e1 - e0 + 7) >> 3;
  int i = e0;

  for (int q = 0; q < niter; q++) {
    #pragma unroll
    for (int k = 0; k < 8; k++) nv[k] = loadrow(i + 8 + k);

    float p[8];
    #pragma unroll
    for (int k = 0; k < 8; k++) {
      half8_t m  = cv[k] + vxr;
      half8_t lm = __builtin_elementwise_max(m, m * (_Float16)0.2f);
      float s = 0.f;
      #pragma unroll
      for (int d2 = 0; d2 < 4; d2++) {
        half2_t a  = { vat[2 * d2], vat[2 * d2 + 1] };
        half2_t x0 = { lm[2 * d2],  lm[2 * d2 + 1]  };
        s = __builtin_amdgcn_fdot2(x0, a, s, false);
      }
      p[k] = s;
    }
    #pragma unroll
    for (int d2 = 1; d2 < 32; d2 <<= 1)
      #pragma unroll
      for (int k = 0; k < 8; k++)
        p[k] += __shfl_xor(p[k], d2);
    #pragma unroll
    for (int k = 1; k < 8; k++)
      if (i + k >= e1) p[k] = -INFINITY;    // masked tail edges -> pe=0

    float m01 = fmaxf(p[0], p[1]), m23 = fmaxf(p[2], p[3]);
    float m45 = fmaxf(p[4], p[5]), m67 = fmaxf(p[6], p[7]);
    float mg = fmaxf(fmaxf(m01, m23), fmaxf(m45, m67));
    if (mg > m_run) {
      float sc = __expf(m_run - mg);        // exp(-inf)=0 on first group
      d_run *= sc;
      accv = accv * (_Float16)sc;
      m_run = mg;
    }
    float pe[8];
    #pragma unroll
    for (int k = 0; k < 8; k++) pe[k] = __expf(p[k] - m_run);
    d_run += ((pe[0] + pe[1]) + (pe[2] + pe[3])) + ((pe[4] + pe[5]) + (pe[6] + pe[7]));
    #pragma unroll
    for (int k = 0; k < 8; k++)
      accv = accv + cv[k] * (_Float16)pe[k];  // v_pk_fma_f16 x4 each
    #pragma unroll
    for (int k = 0; k < 8; k++) cv[k] = nv[k];
    i += 8;
  }

  const float w = 0.125f / (d_run + 1e-16f);
  #pragma unroll
  for (int j = 0; j < 8; j++) red2[j][t] = (float)accv[j] * w;
  __syncthreads();
  if (t < 32) {
    #pragma unroll
    for (int j = 0; j < 8; j++) {
      float s2 = 0.f;
      #pragma unroll
      for (int hh = 0; hh < 8; hh++) s2 += red2[j][hh * 32 + t];
      s2 += bias[t * 8 + j];
      hout16[(size_t)n * CCH + t * 8 + j] = (_Float16)s2;
    }
  }
}

// ---------------------------------------------------------------- pool + head (fp16 h)
__global__ __launch_bounds__(256) void pool_kernel2(
    const _Float16* __restrict__ h16, const int* __restrict__ goff,
    float* __restrict__ pooled)
{
  const int g = blockIdx.x, s = blockIdx.y, t = threadIdx.x;
  const int n0 = goff[g], n1 = goff[g + 1];
  const int len = n1 - n0;
  const int chunk = (len + 7) / 8;
  const int a = n0 + s * chunk;
  const int b = min(a + chunk, n1);
  float sum = 0.f;
  for (int n = a; n < b; n++) sum += (float)h16[(size_t)n * CCH + t];
  if (len > 0) atomicAdd(&pooled[g * CCH + t], sum);
}

__global__ void head_kernel(const float* __restrict__ pooled, const int* __restrict__ goff,
                            const float* __restrict__ hw, const float* __restrict__ hb,
                            float* __restrict__ out)
{
  __shared__ float r[256];
  const int g = blockIdx.x, t = threadIdx.x;
  float c = (float)(goff[g + 1] - goff[g]);
  if (c < 1.f) c = 1.f;
  r[t] = pooled[g * CCH + t] / c * hw[t];
  __syncthreads();
  for (int s2 = 128; s2 > 0; s2 >>= 1) {
    if (t < s2) r[t] += r[t + s2];
    __syncthreads();
  }
  if (t == 0) out[g] = r[0] + hb[0];
}

// ---------------------------------------------------------------- launcher
extern "C" void kernel_launch(void* const* d_in, const int* in_sizes, int n_in,
                              void* d_out, int out_size, void* d_ws, size_t ws_size,
                              hipStream_t stream)
{
  const float* x        = (const float*)d_in[0];
  const int*   ei       = (const int*)d_in[1];
  const int*   batch    = (const int*)d_in[2];
  const float* dense_w  = (const float*)d_in[3];
  const float* dense_b  = (const float*)d_in[4];
  const float* conv_wl  = (const float*)d_in[5];
  const float* conv_wr  = (const float*)d_in[6];
  const float* conv_att = (const float*)d_in[7];
  const float* conv_b   = (const float*)d_in[8];
  const float* head_w   = (const float*)d_in[9];
  const float* head_b   = (const float*)d_in[10];
  float* out = (float*)d_out;

  char* ws = (char*)d_ws;
  size_t off_b = 0;
  auto alloc = [&](size_t bytes) -> char* {
    char* r = ws + off_b;
    off_b += (bytes + 255) & ~(size_t)255;
    return r;
  };
  _Float16*  h16    = (_Float16*)alloc((size_t)M_PAD * CCH * 2);
  _Float16*  x16    = (_Float16*)alloc((size_t)M_PAD * KD_PAD * 2);
  _Float16*  xlr16  = (_Float16*)alloc((size_t)M_PAD * HC2 * 2);
  _Float16*  wdT    = (_Float16*)alloc((size_t)CCH * KD_PAD * 2);
  _Float16*  wcat   = (_Float16*)alloc((size_t)LAYERS * HC2 * CCH * 2);
  int*   offs   = (int*)alloc((N_NODES + 1) * 4);
  int*   cnt    = (int*)alloc(N_NODES * 4);
  int*   csr    = (int*)alloc(E_TOT * 4);
  int*   goff   = (int*)alloc((NGR + 1) * 4);
  float* pooled = (float*)alloc(NGR * CCH * 4);

  // ---- CSR by dst + graph boundaries
  hipMemsetAsync(cnt, 0, N_NODES * 4, stream);
  degree_kernel<<<(E_TOT + 255) / 256, 256, 0, stream>>>(ei, cnt);
  scan_kernel<<<1, 1024, 0, stream>>>(cnt, offs, N_NODES);
  copy_kernel<<<(N_NODES + 255) / 256, 256, 0, stream>>>(offs, cnt, N_NODES);
  fill_kernel<<<(E_TOT + 255) / 256, 256, 0, stream>>>(ei, cnt, csr);
  gbound_kernel<<<(N_NODES + 255) / 256, 256, 0, stream>>>(batch, goff);

  // ---- fp16 conversions / weight transposes (wl|wr concatenated)
  {
    dim3 g(KD_PAD / 256, M_PAD);
    conv_x<<<g, 256, 0, stream>>>(x, x16);
  }
  transpose_w<<<dim3(CCH / 32, KD_PAD / 32), 256, 0, stream>>>(dense_w, wdT, FEAT, CCH, KD_PAD);
  transpose_w8<<<dim3(HC / 32, CCH / 32, 2 * LAYERS), 256, 0, stream>>>(
      conv_wl, conv_wr, wcat);

  // ---- dense: h16 = fp16(x @ dense_w + dense_b)
  gemm_h16<<<dim3(CCH / 128, M_PAD / 128), 256, 0, stream>>>(
      x16, wdT, h16, dense_b, N_NODES, CCH, KD_PAD);

  // ---- 4 GATv2 layers
  for (int l = 0; l < LAYERS; l++) {
    gemm_h16<<<dim3(HC2 / 128, M_PAD / 128), 256, 0, stream>>>(
        h16, wcat + (size_t)l * HC2 * CCH, xlr16, nullptr, N_NODES, HC2, CCH);
    gat_edge<<<N_NODES, 256, 0, stream>>>(xlr16, offs, csr,
                                          conv_att + (size_t)l * HC,
                                          conv_b + (size_t)l * CCH, h16);
  }

  // ---- global mean pool + head
  hipMemsetAsync(pooled, 0, NGR * CCH * 4, stream);
  pool_kernel2<<<dim3(NGR, 8), 256, 0, stream>>>(h16, goff, pooled);
  head_kernel<<<NGR, 256, 0, stream>>>(pooled, goff, head_w, head_b, out);
}